// Round 1
// baseline (7954.579 us; speedup 1.0000x reference)
//
#include <hip/hip_runtime.h>
#include <stdint.h>

// EncDecAD: encoder LSTM (256 steps) -> Linear -> self-feeding decoder LSTM (256 steps).
// Persistent kernel: 256 blocks (1/CU), 16 groups x 16 blocks; group = 32 batch rows,
// block = 16 h-cols (64 gate rows, ifgo grouped). Weights resident as MFMA B-frags in
// VGPRs. Per-step group barrier: sc-coherent (AGENT atomic) h stores + waitcnt +
// monotonic counter (starts at ws poison 0xAAAAAAAA) + acquire fence (buffer_inv).
// ws usage: 4 KiB barrier counters + 3 x (512x256) bf16 h slots = ~772 KiB.

#define H_ 256
#define B_ 512
#define T_ 256
#define GBLK 16  // blocks per group

typedef short short8 __attribute__((ext_vector_type(8)));
typedef float f32x4 __attribute__((ext_vector_type(4)));

__device__ __forceinline__ short f2bf(float f) {
  union { float f; uint32_t u; } v; v.f = f;
  uint32_t r = (v.u + 0x7FFFu + ((v.u >> 16) & 1u)) >> 16;  // RNE
  return (short)(uint16_t)r;
}

__device__ __forceinline__ short8 load8f_bf(const float* __restrict__ p) {
  const float4 a = *(const float4*)p;
  const float4 b = *(const float4*)(p + 4);
  short8 r;
  r[0] = f2bf(a.x); r[1] = f2bf(a.y); r[2] = f2bf(a.z); r[3] = f2bf(a.w);
  r[4] = f2bf(b.x); r[5] = f2bf(b.y); r[6] = f2bf(b.z); r[7] = f2bf(b.w);
  return r;
}

__device__ __forceinline__ float sigm(float x) { return 1.0f / (1.0f + __expf(-x)); }
__device__ __forceinline__ float tanh_(float x) { return 1.0f - 2.0f / (1.0f + __expf(2.0f * x)); }

__global__ __launch_bounds__(256, 1) void encdec_kernel(
    const float* __restrict__ x,
    const float* __restrict__ Wih1, const float* __restrict__ Whh1,
    const float* __restrict__ bih1, const float* __restrict__ bhh1,
    const float* __restrict__ W1,   const float* __restrict__ b1,
    const float* __restrict__ Wih2, const float* __restrict__ Whh2,
    const float* __restrict__ bih2, const float* __restrict__ bhh2,
    float* __restrict__ out,
    uint32_t* __restrict__ bar,
    uint16_t* __restrict__ hbuf)
{
  const int tid = threadIdx.x;
  const int l   = tid & 63;
  const int w   = tid >> 6;          // wave 0..3
  const int blk = blockIdx.x;
  // group members share blockIdx%8 -> same-XCD heuristic (locality only)
  const int gid = (blk & 7) | ((blk >> 7) << 3);   // 0..15
  const int mid = (blk >> 3) & 15;                 // member 0..15
  const int bg  = gid * 32;                        // group batch offset
  const int c0  = mid * 16 + w * 4;                // wave's first h-col

  const int nl   = l & 15;   // MFMA n (and A-row m) index
  const int kc   = l >> 4;   // k quad
  const int gate = nl >> 2;  // 0:i 1:f 2:g 3:o
  const int cm   = nl & 3;
  const int colg = c0 + cm;                 // lane's h-column
  const int grow = gate * H_ + colg;        // global gate row (PyTorch ifgo order)

  uint32_t* cnt = bar + (size_t)gid * 64;   // 256B apart per group
  uint32_t level = 0;

  uint16_t* slot0 = hbuf;
  uint16_t* slot1 = hbuf + (size_t)B_ * H_;
  uint16_t* slot2 = hbuf + (size_t)2 * B_ * H_;
  uint16_t* slots[2] = { slot0, slot1 };

  // ---- encoder weight fragments (B-operand: lane holds W[n=l&15][k=quad*8+j]) ----
  short8 fwa[8], fwb[8];
#pragma unroll
  for (int kt = 0; kt < 8; ++kt) {
    fwa[kt] = load8f_bf(Wih1 + (size_t)grow * H_ + kt * 32 + kc * 8);
    fwb[kt] = load8f_bf(Whh1 + (size_t)grow * H_ + kt * 32 + kc * 8);
  }
  float bias = bih1[grow] + bhh1[grow];

  float cst[2][4];
#pragma unroll
  for (int mt = 0; mt < 2; ++mt)
#pragma unroll
    for (int r = 0; r < 4; ++r) cst[mt][r] = 0.0f;

  auto barrier = [&]() {
    asm volatile("s_waitcnt vmcnt(0)" ::: "memory");  // my sc-stores reached LLC
    __syncthreads();                                   // whole block drained
    ++level;
    if (tid == 0) {
      __hip_atomic_fetch_add(cnt, 1u, __ATOMIC_RELAXED, __HIP_MEMORY_SCOPE_AGENT);
      const uint32_t target = (uint32_t)GBLK * level;
      int guard = 0;
      while ((uint32_t)(__hip_atomic_load(cnt, __ATOMIC_RELAXED, __HIP_MEMORY_SCOPE_AGENT)
                        - 0xAAAAAAAAu) < target) {
        __builtin_amdgcn_s_sleep(1);
        if (++guard > 2000000) break;  // safety: fail wrong, not hung
      }
    }
    __syncthreads();
    __builtin_amdgcn_fence(__ATOMIC_ACQUIRE, "agent");  // inv L1/L2 before peer reads
  };

  // ---------------- encoder ----------------
  for (int t = 0; t < T_; ++t) {
    f32x4 acc[2] = { {0.f,0.f,0.f,0.f}, {0.f,0.f,0.f,0.f} };
#pragma unroll
    for (int mt = 0; mt < 2; ++mt) {
      const float* xr = x + ((size_t)(bg + mt * 16 + nl) * T_ + t) * H_ + kc * 8;
#pragma unroll
      for (int kt = 0; kt < 8; ++kt) {
        short8 af = load8f_bf(xr + kt * 32);
        acc[mt] = __builtin_amdgcn_mfma_f32_16x16x32_bf16(af, fwa[kt], acc[mt], 0, 0, 0);
      }
    }
    if (t > 0) {
      const uint16_t* hs = slots[t & 1];
#pragma unroll
      for (int mt = 0; mt < 2; ++mt) {
        const uint16_t* hr = hs + (size_t)(bg + mt * 16 + nl) * H_ + kc * 8;
#pragma unroll
        for (int kt = 0; kt < 8; ++kt) {
          short8 af = *(const short8*)(hr + kt * 32);
          acc[mt] = __builtin_amdgcn_mfma_f32_16x16x32_bf16(af, fwb[kt], acc[mt], 0, 0, 0);
        }
      }
    }
    uint16_t* hw = slots[(t + 1) & 1];
#pragma unroll
    for (int mt = 0; mt < 2; ++mt) {
#pragma unroll
      for (int r = 0; r < 4; ++r) {
        float z = acc[mt][r] + bias;                    // C: row=(l>>4)*4+r, col=l&15
        float a = (gate == 2) ? tanh_(z) : sigm(z);
        int base = (l & 48) | cm;
        float ti = __shfl(a, base,      64);
        float tf = __shfl(a, base | 4,  64);
        float tg = __shfl(a, base | 8,  64);
        float to = __shfl(a, base | 12, 64);
        float cn = tf * cst[mt][r] + ti * tg;
        cst[mt][r] = cn;
        float hn = to * tanh_(cn);
        if (gate == 0) {
          int b = bg + mt * 16 + kc * 4 + r;
          __hip_atomic_store(&hw[(size_t)b * H_ + colg], (uint16_t)f2bf(hn),
                             __ATOMIC_RELAXED, __HIP_MEMORY_SCOPE_AGENT);
        }
      }
    }
    barrier();
  }

  // ---------------- x_end = h1 @ W1.T + b1  (h1 in slot0) ----------------
  {
    const int xcol = mid * 16 + nl;
    short8 fw1[8];
#pragma unroll
    for (int kt = 0; kt < 8; ++kt)
      fw1[kt] = load8f_bf(W1 + (size_t)xcol * H_ + kt * 32 + kc * 8);
    f32x4 acc[2] = { {0.f,0.f,0.f,0.f}, {0.f,0.f,0.f,0.f} };
#pragma unroll
    for (int mt = 0; mt < 2; ++mt) {
      const uint16_t* hr = slot0 + (size_t)(bg + mt * 16 + nl) * H_ + kc * 8;
#pragma unroll
      for (int kt = 0; kt < 8; ++kt) {
        short8 af = *(const short8*)(hr + kt * 32);
        acc[mt] = __builtin_amdgcn_mfma_f32_16x16x32_bf16(af, fw1[kt], acc[mt], 0, 0, 0);
      }
    }
    float bb = b1[xcol];
    if (w == 0) {  // all 4 waves computed identically; one writes
#pragma unroll
      for (int mt = 0; mt < 2; ++mt)
#pragma unroll
        for (int r = 0; r < 4; ++r) {
          int b = bg + mt * 16 + kc * 4 + r;
          __hip_atomic_store(&slot2[(size_t)b * H_ + xcol], (uint16_t)f2bf(acc[mt][r] + bb),
                             __ATOMIC_RELAXED, __HIP_MEMORY_SCOPE_AGENT);
        }
    }
  }
  // decoder weights (read-only global; safe to load before the barrier)
#pragma unroll
  for (int kt = 0; kt < 8; ++kt) {
    fwa[kt] = load8f_bf(Wih2 + (size_t)grow * H_ + kt * 32 + kc * 8);
    fwb[kt] = load8f_bf(Whh2 + (size_t)grow * H_ + kt * 32 + kc * 8);
  }
  bias = bih2[grow] + bhh2[grow];
  barrier();

  // ---------------- decoder (out feeds back; out==h for t>=1) ----------------
  for (int t = 0; t < T_; ++t) {
    const uint16_t* hsA = (t == 0) ? slot2 : slots[t & 1];  // input x_t
    const uint16_t* hsB = (t == 0) ? slot0 : hsA;           // hidden h_{t-1}
    f32x4 acc[2] = { {0.f,0.f,0.f,0.f}, {0.f,0.f,0.f,0.f} };
#pragma unroll
    for (int mt = 0; mt < 2; ++mt) {
      const uint16_t* hrA = hsA + (size_t)(bg + mt * 16 + nl) * H_ + kc * 8;
      const uint16_t* hrB = hsB + (size_t)(bg + mt * 16 + nl) * H_ + kc * 8;
#pragma unroll
      for (int kt = 0; kt < 8; ++kt) {
        short8 afA = *(const short8*)(hrA + kt * 32);
        acc[mt] = __builtin_amdgcn_mfma_f32_16x16x32_bf16(afA, fwa[kt], acc[mt], 0, 0, 0);
        short8 afB = *(const short8*)(hrB + kt * 32);
        acc[mt] = __builtin_amdgcn_mfma_f32_16x16x32_bf16(afB, fwb[kt], acc[mt], 0, 0, 0);
      }
    }
    uint16_t* hw = slots[(t + 1) & 1];
    const int j = (t == T_ - 1) ? (T_ - 1) : (T_ - 2 - t);  // faithful index replay
#pragma unroll
    for (int mt = 0; mt < 2; ++mt) {
#pragma unroll
      for (int r = 0; r < 4; ++r) {
        float z = acc[mt][r] + bias;
        float a = (gate == 2) ? tanh_(z) : sigm(z);
        int base = (l & 48) | cm;
        float ti = __shfl(a, base,      64);
        float tf = __shfl(a, base | 4,  64);
        float tg = __shfl(a, base | 8,  64);
        float to = __shfl(a, base | 12, 64);
        float cn = tf * cst[mt][r] + ti * tg;
        cst[mt][r] = cn;
        float hn = to * tanh_(cn);
        if (gate == 0) {
          int b = bg + mt * 16 + kc * 4 + r;
          __hip_atomic_store(&hw[(size_t)b * H_ + colg], (uint16_t)f2bf(hn),
                             __ATOMIC_RELAXED, __HIP_MEMORY_SCOPE_AGENT);
          out[((size_t)b * T_ + j) * H_ + colg] = hn;      // fp32 output
        }
      }
    }
    if (t != T_ - 1) barrier();
  }
}

extern "C" void kernel_launch(void* const* d_in, const int* in_sizes, int n_in,
                              void* d_out, int out_size, void* d_ws, size_t ws_size,
                              hipStream_t stream) {
  const float* x    = (const float*)d_in[0];
  const float* Wih1 = (const float*)d_in[1];
  const float* Whh1 = (const float*)d_in[2];
  const float* bih1 = (const float*)d_in[3];
  const float* bhh1 = (const float*)d_in[4];
  const float* W1   = (const float*)d_in[5];
  const float* b1   = (const float*)d_in[6];
  const float* Wih2 = (const float*)d_in[7];
  const float* Whh2 = (const float*)d_in[8];
  const float* bih2 = (const float*)d_in[9];
  const float* bhh2 = (const float*)d_in[10];
  float* out = (float*)d_out;

  uint32_t* bar  = (uint32_t*)d_ws;                       // 4 KiB of counters (poison-based)
  uint16_t* hbuf = (uint16_t*)((char*)d_ws + 4096);       // 3 bf16 h slots

  hipLaunchKernelGGL(encdec_kernel, dim3(256), dim3(256), 0, stream,
                     x, Wih1, Whh1, bih1, bhh1, W1, b1, Wih2, Whh2, bih2, bhh2,
                     out, bar, hbuf);
}

// Round 2
// 7594.978 us; speedup vs baseline: 1.0473x; 1.0473x over previous
//
#include <hip/hip_runtime.h>
#include <stdint.h>

// EncDecAD: encoder LSTM (256 steps) -> Linear -> self-feeding decoder LSTM (256 steps).
// Persistent kernel: 256 blocks (1/CU), 16 groups x 16 blocks; group = 32 batch rows,
// block = 16 h-cols. Weights resident as MFMA B-frags in VGPRs.
// R2: latency-optimized exchange. No fence/buffer_inv, no __syncthreads in step loop.
//  - h exchange: agent-scope relaxed atomic stores (2B) / loads (8B) == sc0 sc1, MALL-coherent.
//  - barrier: per-WAVE flag (64 per group, one 4B slot each), all waves poll 64 flags
//    with a single 64-lane load; poison 0xAAAAAAAA is negative as int -> "not arrived".
//  - encoder x-part MFMAs run in the poll window (independent of h).
//  - decoder t>=1 uses merged weights Wd = Wih2+Whh2 since x_t == h_{t-1} (half the MFMAs).
//  - gate-spread epilogue: gate-group g stores row r=g -> coalesced 64-lane stores.

#define H_ 256
#define B_ 512
#define T_ 256

typedef short short8 __attribute__((ext_vector_type(8)));
typedef float f32x4 __attribute__((ext_vector_type(4)));

__device__ __forceinline__ short f2bf(float f) {
  union { float f; uint32_t u; } v; v.f = f;
  uint32_t r = (v.u + 0x7FFFu + ((v.u >> 16) & 1u)) >> 16;  // RNE
  return (short)(uint16_t)r;
}

__device__ __forceinline__ short8 load8f_bf(const float* __restrict__ p) {
  const float4 a = *(const float4*)p;
  const float4 b = *(const float4*)(p + 4);
  short8 r;
  r[0]=f2bf(a.x); r[1]=f2bf(a.y); r[2]=f2bf(a.z); r[3]=f2bf(a.w);
  r[4]=f2bf(b.x); r[5]=f2bf(b.y); r[6]=f2bf(b.z); r[7]=f2bf(b.w);
  return r;
}

__device__ __forceinline__ short8 load8f_bf_sum(const float* __restrict__ p,
                                                const float* __restrict__ q) {
  const float4 a = *(const float4*)p, b = *(const float4*)(p + 4);
  const float4 c = *(const float4*)q, d = *(const float4*)(q + 4);
  short8 r;
  r[0]=f2bf(a.x+c.x); r[1]=f2bf(a.y+c.y); r[2]=f2bf(a.z+c.z); r[3]=f2bf(a.w+c.w);
  r[4]=f2bf(b.x+d.x); r[5]=f2bf(b.y+d.y); r[6]=f2bf(b.z+d.z); r[7]=f2bf(b.w+d.w);
  return r;
}

// Coherent 16B read of peer-written bf16 data (2x 8B agent atomics -> sc0 sc1 loads).
__device__ __forceinline__ short8 coh_load16(const uint16_t* p) {
  union { uint64_t u[2]; short8 v; } r;
  const uint64_t* q = (const uint64_t*)p;
  r.u[0] = __hip_atomic_load(q,     __ATOMIC_RELAXED, __HIP_MEMORY_SCOPE_AGENT);
  r.u[1] = __hip_atomic_load(q + 1, __ATOMIC_RELAXED, __HIP_MEMORY_SCOPE_AGENT);
  return r.v;
}

__device__ __forceinline__ void coh_store2(uint16_t* p, uint16_t v) {
  __hip_atomic_store(p, v, __ATOMIC_RELAXED, __HIP_MEMORY_SCOPE_AGENT);
}

__device__ __forceinline__ float sigm(float x)  { return 1.0f / (1.0f + __expf(-x)); }
__device__ __forceinline__ float tanh_(float x) { return 1.0f - 2.0f / (1.0f + __expf(2.0f * x)); }

__global__ __launch_bounds__(256, 1) void encdec_kernel(
    const float* __restrict__ x,
    const float* __restrict__ Wih1, const float* __restrict__ Whh1,
    const float* __restrict__ bih1, const float* __restrict__ bhh1,
    const float* __restrict__ W1,   const float* __restrict__ b1,
    const float* __restrict__ Wih2, const float* __restrict__ Whh2,
    const float* __restrict__ bih2, const float* __restrict__ bhh2,
    float* __restrict__ out,
    uint32_t* __restrict__ bar,
    uint16_t* __restrict__ hbuf)
{
  const int tid = threadIdx.x;
  const int l   = tid & 63;
  const int w   = tid >> 6;
  const int blk = blockIdx.x;
  const int gid = (blk & 7) | ((blk >> 7) << 3);   // group: same blk%8 -> same XCD
  const int mid = (blk >> 3) & 15;
  const int bg  = gid * 32;
  const int c0  = mid * 16 + w * 4;

  const int nl   = l & 15;
  const int kc   = l >> 4;
  const int gate = nl >> 2;
  const int cm   = nl & 3;
  const int colg = c0 + cm;
  const int grow = gate * H_ + colg;

  uint32_t* flags = bar + (size_t)gid * 64;   // 64 wave-flags (4B) per group, 256B apart
  const int myflag = mid * 4 + w;

  uint16_t* slot0 = hbuf;
  uint16_t* slot1 = hbuf + (size_t)B_ * H_;
  uint16_t* slot2 = hbuf + (size_t)2 * B_ * H_;

  // wave publishes "my stores (and all prior) are at MALL; state level = target"
  auto arrive = [&](int target) {
    asm volatile("s_waitcnt vmcnt(0)" ::: "memory");   // write-through stores complete
    if (l == 0)
      __hip_atomic_store(&flags[myflag], (uint32_t)target,
                         __ATOMIC_RELAXED, __HIP_MEMORY_SCOPE_AGENT);
  };
  // wave waits until all 64 group waves reached target (poison = negative int)
  auto poll = [&](int target) {
    int g = 0;
    while ((int)__hip_atomic_load(&flags[l], __ATOMIC_RELAXED,
                                  __HIP_MEMORY_SCOPE_AGENT) < target) {
      __builtin_amdgcn_s_sleep(1);
      if (++g > 2000000) break;  // fail-wrong, not hang
    }
    asm volatile("" ::: "memory");  // no motion of h loads above the poll
  };

  // ---- encoder weight fragments (B-operand: lane = W[n=nl][k=kc*8+j]) ----
  short8 fwa[8], fwb[8];
#pragma unroll
  for (int kt = 0; kt < 8; ++kt) {
    fwa[kt] = load8f_bf(Wih1 + (size_t)grow * H_ + kt * 32 + kc * 8);
    fwb[kt] = load8f_bf(Whh1 + (size_t)grow * H_ + kt * 32 + kc * 8);
  }
  float bias = bih1[grow] + bhh1[grow];

  float cst[2][4];
#pragma unroll
  for (int mt = 0; mt < 2; ++mt)
#pragma unroll
    for (int r = 0; r < 4; ++r) cst[mt][r] = 0.0f;

  // x-part MFMAs for step t (independent of h) -> runs in the poll window
  f32x4 accN[2];
  auto xmfma = [&](int t) {
#pragma unroll
    for (int mt = 0; mt < 2; ++mt) {
      f32x4 a = {0.f, 0.f, 0.f, 0.f};
      const float* xr = x + ((size_t)(bg + mt * 16 + nl) * T_ + t) * H_ + kc * 8;
#pragma unroll
      for (int kt = 0; kt < 8; ++kt) {
        short8 af = load8f_bf(xr + kt * 32);
        a = __builtin_amdgcn_mfma_f32_16x16x32_bf16(af, fwa[kt], a, 0, 0, 0);
      }
      accN[mt] = a;
    }
  };
  xmfma(0);

  // ---------------- encoder ----------------
  for (int t = 0; t < T_; ++t) {
    f32x4 acc[2] = { accN[0], accN[1] };
    if (t > 0) {
      poll(t);
      const uint16_t* hs = (t & 1) ? slot1 : slot0;
      short8 hA[2][8];
#pragma unroll
      for (int mt = 0; mt < 2; ++mt)
#pragma unroll
        for (int kt = 0; kt < 8; ++kt)
          hA[mt][kt] = coh_load16(hs + (size_t)(bg + mt * 16 + nl) * H_ + kt * 32 + kc * 8);
#pragma unroll
      for (int mt = 0; mt < 2; ++mt)
#pragma unroll
        for (int kt = 0; kt < 8; ++kt)
          acc[mt] = __builtin_amdgcn_mfma_f32_16x16x32_bf16(hA[mt][kt], fwb[kt], acc[mt], 0, 0, 0);
    }
    uint16_t* hw = ((t + 1) & 1) ? slot1 : slot0;
    const int rb = (l & 48) | cm;
#pragma unroll
    for (int mt = 0; mt < 2; ++mt) {
      float hn = 0.f;
#pragma unroll
      for (int r = 0; r < 4; ++r) {
        float z = acc[mt][r] + bias;
        float a = (gate == 2) ? tanh_(z) : sigm(z);
        float ti = __shfl(a, rb,      64);
        float tf = __shfl(a, rb | 4,  64);
        float tg = __shfl(a, rb | 8,  64);
        float to = __shfl(a, rb | 12, 64);
        float cn = tf * cst[mt][r] + ti * tg;
        cst[mt][r] = cn;
        if (r == gate) hn = to * tanh_(cn);   // only the row this gate-group stores
      }
      const int b = bg + mt * 16 + kc * 4 + gate;
      coh_store2(&hw[(size_t)b * H_ + colg], (uint16_t)f2bf(hn));
    }
    arrive(t + 1);
    if (t + 1 < T_) xmfma(t + 1);   // poll-window work for next step
  }

  // ---------------- x_end = h1 @ W1.T + b1  (h1 in slot0) ----------------
  poll(T_);
  {
    const int xcol = mid * 16 + nl;
    short8 fw1[8];
#pragma unroll
    for (int kt = 0; kt < 8; ++kt)
      fw1[kt] = load8f_bf(W1 + (size_t)xcol * H_ + kt * 32 + kc * 8);
    f32x4 acc[2] = { {0.f,0.f,0.f,0.f}, {0.f,0.f,0.f,0.f} };
#pragma unroll
    for (int mt = 0; mt < 2; ++mt) {
      const uint16_t* hr = slot0 + (size_t)(bg + mt * 16 + nl) * H_ + kc * 8;
#pragma unroll
      for (int kt = 0; kt < 8; ++kt) {
        short8 af = coh_load16(hr + kt * 32);
        acc[mt] = __builtin_amdgcn_mfma_f32_16x16x32_bf16(af, fw1[kt], acc[mt], 0, 0, 0);
      }
    }
    float bb = b1[xcol];
    if (w == 0) {
#pragma unroll
      for (int mt = 0; mt < 2; ++mt)
#pragma unroll
        for (int r = 0; r < 4; ++r) {
          int b = bg + mt * 16 + kc * 4 + r;
          coh_store2(&slot2[(size_t)b * H_ + xcol], (uint16_t)f2bf(acc[mt][r] + bb));
        }
    }
  }
  arrive(T_ + 1);

  // decoder weight prep in the window: separate frags for t=0, merged for t>=1
  short8 fwa2[8], fwb2[8], fws[8];
#pragma unroll
  for (int kt = 0; kt < 8; ++kt) {
    const float* pa = Wih2 + (size_t)grow * H_ + kt * 32 + kc * 8;
    const float* pb = Whh2 + (size_t)grow * H_ + kt * 32 + kc * 8;
    fwa2[kt] = load8f_bf(pa);
    fwb2[kt] = load8f_bf(pb);
    fws[kt]  = load8f_bf_sum(pa, pb);   // bf16(Wih2+Whh2), summed in fp32
  }
  bias = bih2[grow] + bhh2[grow];
  poll(T_ + 1);

  // ---------------- decoder t=0 (x_end with fwa2, h1 with fwb2) ----------------
  {
    f32x4 acc[2] = { {0.f,0.f,0.f,0.f}, {0.f,0.f,0.f,0.f} };
    short8 hA[2][8], hB[2][8];
#pragma unroll
    for (int mt = 0; mt < 2; ++mt)
#pragma unroll
      for (int kt = 0; kt < 8; ++kt) {
        const size_t ro = (size_t)(bg + mt * 16 + nl) * H_ + kt * 32 + kc * 8;
        hA[mt][kt] = coh_load16(slot2 + ro);
        hB[mt][kt] = coh_load16(slot0 + ro);
      }
#pragma unroll
    for (int mt = 0; mt < 2; ++mt)
#pragma unroll
      for (int kt = 0; kt < 8; ++kt) {
        acc[mt] = __builtin_amdgcn_mfma_f32_16x16x32_bf16(hA[mt][kt], fwa2[kt], acc[mt], 0, 0, 0);
        acc[mt] = __builtin_amdgcn_mfma_f32_16x16x32_bf16(hB[mt][kt], fwb2[kt], acc[mt], 0, 0, 0);
      }
    const int rb = (l & 48) | cm;
    const int j0 = T_ - 2;   // t=0 -> j = T-2
#pragma unroll
    for (int mt = 0; mt < 2; ++mt) {
      float hn = 0.f;
#pragma unroll
      for (int r = 0; r < 4; ++r) {
        float z = acc[mt][r] + bias;
        float a = (gate == 2) ? tanh_(z) : sigm(z);
        float ti = __shfl(a, rb,      64);
        float tf = __shfl(a, rb | 4,  64);
        float tg = __shfl(a, rb | 8,  64);
        float to = __shfl(a, rb | 12, 64);
        float cn = tf * cst[mt][r] + ti * tg;
        cst[mt][r] = cn;
        if (r == gate) hn = to * tanh_(cn);
      }
      const int b = bg + mt * 16 + kc * 4 + gate;
      coh_store2(&slot1[(size_t)b * H_ + colg], (uint16_t)f2bf(hn));
      out[((size_t)b * T_ + j0) * H_ + colg] = hn;
    }
    arrive(T_ + 2);
  }

  // ---------------- decoder t>=1 (merged weights; x_t == h_{t-1}) ----------------
  for (int t = 1; t < T_; ++t) {
    poll(T_ + 1 + t);
    const uint16_t* hs = (t & 1) ? slot1 : slot0;
    f32x4 acc[2] = { {0.f,0.f,0.f,0.f}, {0.f,0.f,0.f,0.f} };
    short8 hA[2][8];
#pragma unroll
    for (int mt = 0; mt < 2; ++mt)
#pragma unroll
      for (int kt = 0; kt < 8; ++kt)
        hA[mt][kt] = coh_load16(hs + (size_t)(bg + mt * 16 + nl) * H_ + kt * 32 + kc * 8);
#pragma unroll
    for (int mt = 0; mt < 2; ++mt)
#pragma unroll
      for (int kt = 0; kt < 8; ++kt)
        acc[mt] = __builtin_amdgcn_mfma_f32_16x16x32_bf16(hA[mt][kt], fws[kt], acc[mt], 0, 0, 0);

    uint16_t* hw = ((t + 1) & 1) ? slot1 : slot0;
    const int j = (t == T_ - 1) ? (T_ - 1) : (T_ - 2 - t);
    const int rb = (l & 48) | cm;
#pragma unroll
    for (int mt = 0; mt < 2; ++mt) {
      float hn = 0.f;
#pragma unroll
      for (int r = 0; r < 4; ++r) {
        float z = acc[mt][r] + bias;
        float a = (gate == 2) ? tanh_(z) : sigm(z);
        float ti = __shfl(a, rb,      64);
        float tf = __shfl(a, rb | 4,  64);
        float tg = __shfl(a, rb | 8,  64);
        float to = __shfl(a, rb | 12, 64);
        float cn = tf * cst[mt][r] + ti * tg;
        cst[mt][r] = cn;
        if (r == gate) hn = to * tanh_(cn);
      }
      const int b = bg + mt * 16 + kc * 4 + gate;
      coh_store2(&hw[(size_t)b * H_ + colg], (uint16_t)f2bf(hn));
      out[((size_t)b * T_ + j) * H_ + colg] = hn;
    }
    if (t + 1 < T_) arrive(T_ + 2 + t);
  }
}

extern "C" void kernel_launch(void* const* d_in, const int* in_sizes, int n_in,
                              void* d_out, int out_size, void* d_ws, size_t ws_size,
                              hipStream_t stream) {
  const float* x    = (const float*)d_in[0];
  const float* Wih1 = (const float*)d_in[1];
  const float* Whh1 = (const float*)d_in[2];
  const float* bih1 = (const float*)d_in[3];
  const float* bhh1 = (const float*)d_in[4];
  const float* W1   = (const float*)d_in[5];
  const float* b1   = (const float*)d_in[6];
  const float* Wih2 = (const float*)d_in[7];
  const float* Whh2 = (const float*)d_in[8];
  const float* bih2 = (const float*)d_in[9];
  const float* bhh2 = (const float*)d_in[10];
  float* out = (float*)d_out;

  uint32_t* bar  = (uint32_t*)d_ws;                  // 16 groups x 64 wave-flags (4 KiB)
  uint16_t* hbuf = (uint16_t*)((char*)d_ws + 4096);  // 3 bf16 (B,H) slots

  hipLaunchKernelGGL(encdec_kernel, dim3(256), dim3(256), 0, stream,
                     x, Wih1, Whh1, bih1, bhh1, W1, b1, Wih2, Whh2, bih2, bhh2,
                     out, bar, hbuf);
}

// Round 3
// 4727.007 us; speedup vs baseline: 1.6828x; 1.6067x over previous
//
#include <hip/hip_runtime.h>
#include <stdint.h>

// EncDecAD: encoder LSTM (256) -> Linear -> self-feeding decoder LSTM (256).
// Persistent: 256 blocks (1/CU), 16 groups x 16 blocks; group = 32 batch rows,
// block = 16 h-cols. Weights resident as MFMA B-frags in VGPRs.
// R3: store-path fix. Epilogue gathers the block's 32x16 h-tile in LDS, then
// 256 threads emit ONE 4B coherent store each -> 32 full 32B sectors, no RMW.
// out[] (fp32) gathered likewise and stored with normal cached stores AFTER the
// flag publish (drains in the poll window). Flags spread 1/sector. LDS barrier
// is raw s_barrier + lgkmcnt only (no vmcnt drain).

#define H_ 256
#define B_ 512
#define T_ 256

typedef short short8 __attribute__((ext_vector_type(8)));
typedef float f32x4 __attribute__((ext_vector_type(4)));

__device__ __forceinline__ short f2bf(float f) {
  union { float f; uint32_t u; } v; v.f = f;
  uint32_t r = (v.u + 0x7FFFu + ((v.u >> 16) & 1u)) >> 16;  // RNE
  return (short)(uint16_t)r;
}

__device__ __forceinline__ short8 load8f_bf(const float* __restrict__ p) {
  const float4 a = *(const float4*)p;
  const float4 b = *(const float4*)(p + 4);
  short8 r;
  r[0]=f2bf(a.x); r[1]=f2bf(a.y); r[2]=f2bf(a.z); r[3]=f2bf(a.w);
  r[4]=f2bf(b.x); r[5]=f2bf(b.y); r[6]=f2bf(b.z); r[7]=f2bf(b.w);
  return r;
}

__device__ __forceinline__ short8 load8f_bf_sum(const float* __restrict__ p,
                                                const float* __restrict__ q) {
  const float4 a = *(const float4*)p, b = *(const float4*)(p + 4);
  const float4 c = *(const float4*)q, d = *(const float4*)(q + 4);
  short8 r;
  r[0]=f2bf(a.x+c.x); r[1]=f2bf(a.y+c.y); r[2]=f2bf(a.z+c.z); r[3]=f2bf(a.w+c.w);
  r[4]=f2bf(b.x+d.x); r[5]=f2bf(b.y+d.y); r[6]=f2bf(b.z+d.z); r[7]=f2bf(b.w+d.w);
  return r;
}

__device__ __forceinline__ short8 coh_load16(const uint16_t* p) {
  union { uint64_t u[2]; short8 v; } r;
  const uint64_t* q = (const uint64_t*)p;
  r.u[0] = __hip_atomic_load(q,     __ATOMIC_RELAXED, __HIP_MEMORY_SCOPE_AGENT);
  r.u[1] = __hip_atomic_load(q + 1, __ATOMIC_RELAXED, __HIP_MEMORY_SCOPE_AGENT);
  return r.v;
}

__device__ __forceinline__ float sigm(float x)  { return 1.0f / (1.0f + __expf(-x)); }
__device__ __forceinline__ float tanh_(float x) { return 1.0f - 2.0f / (1.0f + __expf(2.0f * x)); }

__global__ __launch_bounds__(256, 1) void encdec_kernel(
    const float* __restrict__ x,
    const float* __restrict__ Wih1, const float* __restrict__ Whh1,
    const float* __restrict__ bih1, const float* __restrict__ bhh1,
    const float* __restrict__ W1,   const float* __restrict__ b1,
    const float* __restrict__ Wih2, const float* __restrict__ Whh2,
    const float* __restrict__ bih2, const float* __restrict__ bhh2,
    float* __restrict__ out,
    uint32_t* __restrict__ bar,
    uint16_t* __restrict__ hbuf)
{
  __shared__ uint16_t hsh[32][16];  // block's h tile (b_loc x col16), bf16
  __shared__ float    osh[32][16];  // block's out tile, fp32 (decoder)

  const int tid = threadIdx.x;
  const int l   = tid & 63;
  const int w   = tid >> 6;
  const int blk = blockIdx.x;
  const int gid = (blk & 7) | ((blk >> 7) << 3);   // group: same blk%8 (XCD locality)
  const int mid = (blk >> 3) & 15;
  const int bg  = gid * 32;
  const int c0  = mid * 16 + w * 4;

  const int nl   = l & 15;
  const int kc   = l >> 4;
  const int gate = nl >> 2;
  const int cm   = nl & 3;
  const int colg = c0 + cm;
  const int grow = gate * H_ + colg;

  // flags: one 32B sector per wave-flag; 2 KiB per group
  uint32_t* flags = bar + (size_t)gid * 512;
  const int myflag = (mid * 4 + w) * 8;

  uint16_t* slot0 = hbuf;
  uint16_t* slot1 = hbuf + (size_t)B_ * H_;
  uint16_t* slot2 = hbuf + (size_t)2 * B_ * H_;

  auto arrive = [&](int target) {
    asm volatile("s_waitcnt vmcnt(0)" ::: "memory");   // my coherent stores are visible
    if (l == 0)
      __hip_atomic_store(&flags[myflag], (uint32_t)target,
                         __ATOMIC_RELAXED, __HIP_MEMORY_SCOPE_AGENT);
  };
  auto poll = [&](int target) {
    int g = 0;
    while ((int)__hip_atomic_load(&flags[l * 8], __ATOMIC_RELAXED,
                                  __HIP_MEMORY_SCOPE_AGENT) < target) {
      __builtin_amdgcn_s_sleep(1);
      if (++g > 2000000) break;  // fail-wrong, not hang
    }
    asm volatile("" ::: "memory");
  };
  auto ldsbar = [&]() {
    asm volatile("s_waitcnt lgkmcnt(0)\n\ts_barrier" ::: "memory");
  };

  // ---- encoder weight fragments (B-operand: lane = W[n=nl][k=kc*8+j]) ----
  short8 fwa[8], fwb[8];
#pragma unroll
  for (int kt = 0; kt < 8; ++kt) {
    fwa[kt] = load8f_bf(Wih1 + (size_t)grow * H_ + kt * 32 + kc * 8);
    fwb[kt] = load8f_bf(Whh1 + (size_t)grow * H_ + kt * 32 + kc * 8);
  }
  float bias = bih1[grow] + bhh1[grow];

  float cst[2][4];
#pragma unroll
  for (int mt = 0; mt < 2; ++mt)
#pragma unroll
    for (int r = 0; r < 4; ++r) cst[mt][r] = 0.0f;

  // gate math + LDS gather-write (hn only for r==gate; each (mt,kc,gate,cm) is unique)
  auto epi = [&](const f32x4* acc, float bias_, bool wout) {
    const int rb = (l & 48) | cm;
#pragma unroll
    for (int mt = 0; mt < 2; ++mt) {
      float hn = 0.f;
#pragma unroll
      for (int r = 0; r < 4; ++r) {
        float z = acc[mt][r] + bias_;
        float a = (gate == 2) ? tanh_(z) : sigm(z);
        float ti = __shfl(a, rb,      64);
        float tf = __shfl(a, rb | 4,  64);
        float tg = __shfl(a, rb | 8,  64);
        float to = __shfl(a, rb | 12, 64);
        float cn = tf * cst[mt][r] + ti * tg;
        cst[mt][r] = cn;
        if (r == gate) hn = to * tanh_(cn);
      }
      hsh[mt * 16 + kc * 4 + gate][w * 4 + cm] = (uint16_t)f2bf(hn);
      if (wout) osh[mt * 16 + kc * 4 + gate][w * 4 + cm] = hn;
    }
  };

  const int gb = tid >> 3;          // gather: b_loc 0..31
  const int gc = tid & 7;           // 4B chunk within the 32B row-chunk

  // x-part MFMAs for step t (independent of h) -> runs post-flag, pre-poll
  f32x4 accN[2];
  auto xmfma = [&](int t) {
#pragma unroll
    for (int mt = 0; mt < 2; ++mt) {
      f32x4 a = {0.f, 0.f, 0.f, 0.f};
      const float* xr = x + ((size_t)(bg + mt * 16 + nl) * T_ + t) * H_ + kc * 8;
#pragma unroll
      for (int kt = 0; kt < 8; ++kt) {
        short8 af = load8f_bf(xr + kt * 32);
        a = __builtin_amdgcn_mfma_f32_16x16x32_bf16(af, fwa[kt], a, 0, 0, 0);
      }
      accN[mt] = a;
    }
  };
  xmfma(0);

  // ---------------- encoder ----------------
  for (int t = 0; t < T_; ++t) {
    f32x4 acc[2] = { accN[0], accN[1] };
    if (t > 0) {
      poll(t);
      const uint16_t* hs = (t & 1) ? slot1 : slot0;
      short8 hA[2][8];
#pragma unroll
      for (int mt = 0; mt < 2; ++mt)
#pragma unroll
        for (int kt = 0; kt < 8; ++kt)
          hA[mt][kt] = coh_load16(hs + (size_t)(bg + mt * 16 + nl) * H_ + kt * 32 + kc * 8);
#pragma unroll
      for (int mt = 0; mt < 2; ++mt)
#pragma unroll
        for (int kt = 0; kt < 8; ++kt)
          acc[mt] = __builtin_amdgcn_mfma_f32_16x16x32_bf16(hA[mt][kt], fwb[kt], acc[mt], 0, 0, 0);
    }
    epi(acc, bias, false);
    ldsbar();
    uint16_t* hw = ((t + 1) & 1) ? slot1 : slot0;
    {
      uint32_t hv = *(const uint32_t*)&hsh[gb][gc * 2];
      __hip_atomic_store((uint32_t*)&hw[(size_t)(bg + gb) * H_ + mid * 16 + gc * 2], hv,
                         __ATOMIC_RELAXED, __HIP_MEMORY_SCOPE_AGENT);
    }
    arrive(t + 1);
    if (t + 1 < T_) xmfma(t + 1);   // overlapped with peers' arrival
  }

  // ---------------- x_end = h1 @ W1.T + b1  (h1 in slot0) ----------------
  poll(T_);
  {
    const int xcol = mid * 16 + nl;
    short8 fw1[8];
#pragma unroll
    for (int kt = 0; kt < 8; ++kt)
      fw1[kt] = load8f_bf(W1 + (size_t)xcol * H_ + kt * 32 + kc * 8);
    f32x4 acc[2] = { {0.f,0.f,0.f,0.f}, {0.f,0.f,0.f,0.f} };
#pragma unroll
    for (int mt = 0; mt < 2; ++mt) {
      const uint16_t* hr = slot0 + (size_t)(bg + mt * 16 + nl) * H_ + kc * 8;
#pragma unroll
      for (int kt = 0; kt < 8; ++kt) {
        short8 af = coh_load16(hr + kt * 32);
        acc[mt] = __builtin_amdgcn_mfma_f32_16x16x32_bf16(af, fw1[kt], acc[mt], 0, 0, 0);
      }
    }
    float bb = b1[xcol];
    if (w == 0) {  // one wave writes x_end (scattered 2B, one-time)
#pragma unroll
      for (int mt = 0; mt < 2; ++mt)
#pragma unroll
        for (int r = 0; r < 4; ++r) {
          int b = bg + mt * 16 + kc * 4 + r;
          __hip_atomic_store(&slot2[(size_t)b * H_ + mid * 16 + nl], (uint16_t)f2bf(acc[mt][r] + bb),
                             __ATOMIC_RELAXED, __HIP_MEMORY_SCOPE_AGENT);
        }
    }
  }
  arrive(T_ + 1);

  // decoder weight prep in the window
  short8 fwa2[8], fwb2[8], fws[8];
#pragma unroll
  for (int kt = 0; kt < 8; ++kt) {
    const float* pa = Wih2 + (size_t)grow * H_ + kt * 32 + kc * 8;
    const float* pb = Whh2 + (size_t)grow * H_ + kt * 32 + kc * 8;
    fwa2[kt] = load8f_bf(pa);
    fwb2[kt] = load8f_bf(pb);
    fws[kt]  = load8f_bf_sum(pa, pb);   // bf16(Wih2+Whh2), summed in fp32
  }
  bias = bih2[grow] + bhh2[grow];
  poll(T_ + 1);

  // ---------------- decoder t=0 (x_end w/ fwa2, h1 w/ fwb2) ----------------
  {
    f32x4 acc[2] = { {0.f,0.f,0.f,0.f}, {0.f,0.f,0.f,0.f} };
    short8 hA[2][8], hB[2][8];
#pragma unroll
    for (int mt = 0; mt < 2; ++mt)
#pragma unroll
      for (int kt = 0; kt < 8; ++kt) {
        const size_t ro = (size_t)(bg + mt * 16 + nl) * H_ + kt * 32 + kc * 8;
        hA[mt][kt] = coh_load16(slot2 + ro);
        hB[mt][kt] = coh_load16(slot0 + ro);
      }
#pragma unroll
    for (int mt = 0; mt < 2; ++mt)
#pragma unroll
      for (int kt = 0; kt < 8; ++kt) {
        acc[mt] = __builtin_amdgcn_mfma_f32_16x16x32_bf16(hA[mt][kt], fwa2[kt], acc[mt], 0, 0, 0);
        acc[mt] = __builtin_amdgcn_mfma_f32_16x16x32_bf16(hB[mt][kt], fwb2[kt], acc[mt], 0, 0, 0);
      }
    epi(acc, bias, true);
    ldsbar();
    uint32_t hv = *(const uint32_t*)&hsh[gb][gc * 2];
    uint64_t ov = *(const uint64_t*)&osh[gb][gc * 2];
    __hip_atomic_store((uint32_t*)&slot1[(size_t)(bg + gb) * H_ + mid * 16 + gc * 2], hv,
                       __ATOMIC_RELAXED, __HIP_MEMORY_SCOPE_AGENT);
    arrive(T_ + 2);
    *(uint64_t*)&out[((size_t)(bg + gb) * T_ + (T_ - 2)) * H_ + mid * 16 + gc * 2] = ov;
  }

  // ---------------- decoder t>=1 (merged weights; x_t == h_{t-1}) ----------------
  for (int t = 1; t < T_; ++t) {
    poll(T_ + 1 + t);
    const uint16_t* hs = (t & 1) ? slot1 : slot0;
    f32x4 acc[2] = { {0.f,0.f,0.f,0.f}, {0.f,0.f,0.f,0.f} };
    short8 hA[2][8];
#pragma unroll
    for (int mt = 0; mt < 2; ++mt)
#pragma unroll
      for (int kt = 0; kt < 8; ++kt)
        hA[mt][kt] = coh_load16(hs + (size_t)(bg + mt * 16 + nl) * H_ + kt * 32 + kc * 8);
#pragma unroll
    for (int mt = 0; mt < 2; ++mt)
#pragma unroll
      for (int kt = 0; kt < 8; ++kt)
        acc[mt] = __builtin_amdgcn_mfma_f32_16x16x32_bf16(hA[mt][kt], fws[kt], acc[mt], 0, 0, 0);

    epi(acc, bias, true);
    ldsbar();
    const int j = (t == T_ - 1) ? (T_ - 1) : (T_ - 2 - t);
    uint32_t hv = *(const uint32_t*)&hsh[gb][gc * 2];
    uint64_t ov = *(const uint64_t*)&osh[gb][gc * 2];
    if (t + 1 < T_) {
      uint16_t* hw = ((t + 1) & 1) ? slot1 : slot0;
      __hip_atomic_store((uint32_t*)&hw[(size_t)(bg + gb) * H_ + mid * 16 + gc * 2], hv,
                         __ATOMIC_RELAXED, __HIP_MEMORY_SCOPE_AGENT);
      arrive(T_ + 2 + t);
    }
    *(uint64_t*)&out[((size_t)(bg + gb) * T_ + j) * H_ + mid * 16 + gc * 2] = ov;
  }
}

extern "C" void kernel_launch(void* const* d_in, const int* in_sizes, int n_in,
                              void* d_out, int out_size, void* d_ws, size_t ws_size,
                              hipStream_t stream) {
  const float* x    = (const float*)d_in[0];
  const float* Wih1 = (const float*)d_in[1];
  const float* Whh1 = (const float*)d_in[2];
  const float* bih1 = (const float*)d_in[3];
  const float* bhh1 = (const float*)d_in[4];
  const float* W1   = (const float*)d_in[5];
  const float* b1   = (const float*)d_in[6];
  const float* Wih2 = (const float*)d_in[7];
  const float* Whh2 = (const float*)d_in[8];
  const float* bih2 = (const float*)d_in[9];
  const float* bhh2 = (const float*)d_in[10];
  float* out = (float*)d_out;

  uint32_t* bar  = (uint32_t*)d_ws;                   // 16 groups x 2 KiB flag regions
  uint16_t* hbuf = (uint16_t*)((char*)d_ws + 32768);  // 3 bf16 (B,H) slots

  hipLaunchKernelGGL(encdec_kernel, dim3(256), dim3(256), 0, stream,
                     x, Wih1, Whh1, bih1, bhh1, W1, b1, Wih2, Whh2, bih2, bhh2,
                     out, bar, hbuf);
}